// Round 1
// baseline (595.398 us; speedup 1.0000x reference)
//
#include <hip/hip_runtime.h>

#define NDIM 8
#define P_PAIRS 28
#define HID 128
#define BATCH_N 65536
#define TILE_M 256
#define THREADS 512

typedef __attribute__((ext_vector_type(8))) short bf16x8;
typedef __attribute__((ext_vector_type(4))) float f32x4;

__device__ __forceinline__ unsigned short f32_to_bf16(float f) {
  union { float f; unsigned u; } v; v.f = f;
  unsigned r = v.u + 0x7FFFu + ((v.u >> 16) & 1u);
  return (unsigned short)(r >> 16);
}

__device__ __forceinline__ float softplus_f(float z) {
  float e = __expf(z);
  float r = __logf(1.0f + e);
  return (z > 20.0f) ? z : r;
}

// Transpose+convert Wh (2,28,128,128) f32 -> WT (2,28,128,128) bf16 with WT[l][p][n][k] = Wh[l][p][k][n]
__global__ void prep_wt(const float* __restrict__ Wh, unsigned short* __restrict__ WT) {
  __shared__ float tile[32][33];
  int t = blockIdx.x;           // 56*16 blocks
  int lp = t >> 4;
  int sub = t & 15;
  int kt = (sub >> 2) * 32, nt = (sub & 3) * 32;
  const float* src = Wh + (size_t)lp * 16384;
  unsigned short* dst = WT + (size_t)lp * 16384;
  int tx = threadIdx.x & 31, ty = threadIdx.x >> 5;   // 32 x 8
#pragma unroll
  for (int r = 0; r < 32; r += 8)
    tile[r + ty][tx] = src[(kt + r + ty) * 128 + (nt + tx)];
  __syncthreads();
#pragma unroll
  for (int r = 0; r < 32; r += 8)
    dst[(nt + r + ty) * 128 + (kt + tx)] = f32_to_bf16(tile[tx][r + ty]);
}

__launch_bounds__(THREADS, 2)
__global__ void mlp_pairs(const float* __restrict__ x,
                          const float* __restrict__ W1,
                          const float* __restrict__ b1,
                          const float* __restrict__ bh,
                          const float* __restrict__ Wout,
                          const float* __restrict__ bout,
                          const int* __restrict__ rel_idx,
                          const int* __restrict__ i_idx,
                          const int* __restrict__ j_idx,
                          const unsigned short* __restrict__ WT,
                          float* __restrict__ out) {
  const int p = blockIdx.y;
  const int row0 = blockIdx.x * TILE_M;
  const int tid = (int)threadIdx.x;
  const int lane = tid & 63;
  const int wave = tid >> 6;          // 0..7, each wave owns 32 batch rows
  const int qd = lane >> 4;           // quad 0..3
  const int ln = lane & 15;
  const int mrow = wave * 32;

  // padded pitches: 136 bf16 = 272 B (16B-aligned rows, 2-way-max bank conflicts)
  __shared__ __align__(16) unsigned short w_lds[128][136];     // 34816 B (current layer weights, transposed [n][k])
  __shared__ __align__(16) unsigned short h_lds[TILE_M][136];  // 69632 B (activations, row-major [m][k])
  __shared__ __align__(16) unsigned short xg_lds[TILE_M][40];  // 20480 B (gathered input, K padded 6->32)
  __shared__ __align__(16) unsigned short w1t_lds[128][40];    // 10240 B (W1^T [n][k], K padded)
  __shared__ __align__(16) float b1s[128];
  __shared__ __align__(16) float bh0s[128];
  __shared__ __align__(16) float bh1s[128];
  __shared__ __align__(16) float wouts[128];

  // ---- stage Wh0^T into w_lds (coalesced 16B chunks) ----
  {
    const uint4* src = reinterpret_cast<const uint4*>(WT + (size_t)p * 16384);
#pragma unroll
    for (int it = 0; it < 4; ++it) {
      int idx = it * THREADS + tid;    // 0..2047
      int r = idx >> 4, c = idx & 15;
      *reinterpret_cast<uint4*>(&w_lds[r][c * 8]) = src[idx];
    }
  }
  // ---- stage x (gathered, bf16, zero-padded), W1^T, biases ----
  if (tid < TILE_M) {
    int r = tid;
    const float4* xr = reinterpret_cast<const float4*>(x + (size_t)(row0 + r) * 8);
    float4 a = xr[0], b = xr[1];
    float xv[8] = {a.x, a.y, a.z, a.w, b.x, b.y, b.z, b.w};
    uint2 z2; z2.x = 0u; z2.y = 0u;
#pragma unroll
    for (int c = 0; c < 8; ++c)
      *reinterpret_cast<uint2*>(&xg_lds[r][c * 4]) = z2;   // zero k=0..31
#pragma unroll
    for (int d = 0; d < 6; ++d) {
      int rl = rel_idx[p * 6 + d];
      xg_lds[r][d] = f32_to_bf16(xv[rl]);
    }
  } else if (tid < TILE_M + 128) {
    int n = tid - TILE_M;
    uint2 z2; z2.x = 0u; z2.y = 0u;
#pragma unroll
    for (int c = 0; c < 8; ++c)
      *reinterpret_cast<uint2*>(&w1t_lds[n][c * 4]) = z2;
#pragma unroll
    for (int k = 0; k < 6; ++k)
      w1t_lds[n][k] = f32_to_bf16(W1[(p * 6 + k) * 128 + n]);
  } else {
    int n = tid - (TILE_M + 128);      // 0..127
    b1s[n]  = b1[p * 128 + n];
    bh0s[n] = bh[p * 128 + n];
    bh1s[n] = bh[(P_PAIRS + p) * 128 + n];
    wouts[n] = Wout[p * 128 + n];
  }
  __syncthreads();

  f32x4 acc[2][8];

  // ================= Layer 1: h1 = softplus(xg @ W1 + b1), K padded to 32, one MFMA step ============
#pragma unroll
  for (int mt = 0; mt < 2; ++mt)
#pragma unroll
    for (int nt = 0; nt < 8; ++nt)
      acc[mt][nt] = (f32x4){0.f, 0.f, 0.f, 0.f};
  {
    bf16x8 bfr[2], afr[8];
#pragma unroll
    for (int mt = 0; mt < 2; ++mt)
      bfr[mt] = *reinterpret_cast<const bf16x8*>(&xg_lds[mrow + mt * 16 + ln][qd * 8]);
#pragma unroll
    for (int nt = 0; nt < 8; ++nt)
      afr[nt] = *reinterpret_cast<const bf16x8*>(&w1t_lds[nt * 16 + ln][qd * 8]);
#pragma unroll
    for (int nt = 0; nt < 8; ++nt)
#pragma unroll
      for (int mt = 0; mt < 2; ++mt)
        acc[mt][nt] = __builtin_amdgcn_mfma_f32_16x16x32_bf16(afr[nt], bfr[mt], acc[mt][nt], 0, 0, 0);
  }
  // epilogue -> h_lds (row-major, 4 consecutive n per lane -> packed b64 write; wave-private rows)
#pragma unroll
  for (int mt = 0; mt < 2; ++mt) {
    int m = mrow + mt * 16 + ln;
#pragma unroll
    for (int nt = 0; nt < 8; ++nt) {
      f32x4 bias4 = *reinterpret_cast<const f32x4*>(&b1s[nt * 16 + qd * 4]);
      unsigned short u[4];
#pragma unroll
      for (int r = 0; r < 4; ++r)
        u[r] = f32_to_bf16(softplus_f(acc[mt][nt][r] + bias4[r]));
      uint2 pk;
      pk.x = (unsigned)u[0] | ((unsigned)u[1] << 16);
      pk.y = (unsigned)u[2] | ((unsigned)u[3] << 16);
      *reinterpret_cast<uint2*>(&h_lds[m][nt * 16 + qd * 4]) = pk;
    }
  }

  // ================= Layer 2: h2 = softplus(h1 @ Wh0 + bh0), in-place (wave-private rows) ============
#pragma unroll
  for (int mt = 0; mt < 2; ++mt)
#pragma unroll
    for (int nt = 0; nt < 8; ++nt)
      acc[mt][nt] = (f32x4){0.f, 0.f, 0.f, 0.f};
#pragma unroll
  for (int ks = 0; ks < 4; ++ks) {
    bf16x8 bfr[2], afr[8];
#pragma unroll
    for (int mt = 0; mt < 2; ++mt)
      bfr[mt] = *reinterpret_cast<const bf16x8*>(&h_lds[mrow + mt * 16 + ln][ks * 32 + qd * 8]);
#pragma unroll
    for (int nt = 0; nt < 8; ++nt)
      afr[nt] = *reinterpret_cast<const bf16x8*>(&w_lds[nt * 16 + ln][ks * 32 + qd * 8]);
#pragma unroll
    for (int nt = 0; nt < 8; ++nt)
#pragma unroll
      for (int mt = 0; mt < 2; ++mt)
        acc[mt][nt] = __builtin_amdgcn_mfma_f32_16x16x32_bf16(afr[nt], bfr[mt], acc[mt][nt], 0, 0, 0);
  }
#pragma unroll
  for (int mt = 0; mt < 2; ++mt) {
    int m = mrow + mt * 16 + ln;
#pragma unroll
    for (int nt = 0; nt < 8; ++nt) {
      f32x4 bias4 = *reinterpret_cast<const f32x4*>(&bh0s[nt * 16 + qd * 4]);
      unsigned short u[4];
#pragma unroll
      for (int r = 0; r < 4; ++r)
        u[r] = f32_to_bf16(softplus_f(acc[mt][nt][r] + bias4[r]));
      uint2 pk;
      pk.x = (unsigned)u[0] | ((unsigned)u[1] << 16);
      pk.y = (unsigned)u[2] | ((unsigned)u[3] << 16);
      *reinterpret_cast<uint2*>(&h_lds[m][nt * 16 + qd * 4]) = pk;
    }
  }

  // ---- swap weights: Wh1^T into w_lds ----
  __syncthreads();   // all waves done reading Wh0
  {
    const uint4* src = reinterpret_cast<const uint4*>(WT + (size_t)(P_PAIRS + p) * 16384);
#pragma unroll
    for (int it = 0; it < 4; ++it) {
      int idx = it * THREADS + tid;
      int r = idx >> 4, c = idx & 15;
      *reinterpret_cast<uint4*>(&w_lds[r][c * 8]) = src[idx];
    }
  }
  __syncthreads();

  // ================= Layer 3 + output dot, no LDS round trip ============
#pragma unroll
  for (int mt = 0; mt < 2; ++mt)
#pragma unroll
    for (int nt = 0; nt < 8; ++nt)
      acc[mt][nt] = (f32x4){0.f, 0.f, 0.f, 0.f};
#pragma unroll
  for (int ks = 0; ks < 4; ++ks) {
    bf16x8 bfr[2], afr[8];
#pragma unroll
    for (int mt = 0; mt < 2; ++mt)
      bfr[mt] = *reinterpret_cast<const bf16x8*>(&h_lds[mrow + mt * 16 + ln][ks * 32 + qd * 8]);
#pragma unroll
    for (int nt = 0; nt < 8; ++nt)
      afr[nt] = *reinterpret_cast<const bf16x8*>(&w_lds[nt * 16 + ln][ks * 32 + qd * 8]);
#pragma unroll
    for (int nt = 0; nt < 8; ++nt)
#pragma unroll
      for (int mt = 0; mt < 2; ++mt)
        acc[mt][nt] = __builtin_amdgcn_mfma_f32_16x16x32_bf16(afr[nt], bfr[mt], acc[mt][nt], 0, 0, 0);
  }
  float pv[2] = {0.f, 0.f};
#pragma unroll
  for (int mt = 0; mt < 2; ++mt) {
#pragma unroll
    for (int nt = 0; nt < 8; ++nt) {
      f32x4 bias4 = *reinterpret_cast<const f32x4*>(&bh1s[nt * 16 + qd * 4]);
      f32x4 wo4   = *reinterpret_cast<const f32x4*>(&wouts[nt * 16 + qd * 4]);
#pragma unroll
      for (int r = 0; r < 4; ++r)
        pv[mt] += wo4[r] * softplus_f(acc[mt][nt][r] + bias4[r]);
    }
  }

  const int ii = i_idx[p], jj = j_idx[p];
  const float bp = bout[p];
#pragma unroll
  for (int mt = 0; mt < 2; ++mt) {
    float v = pv[mt];
    v += __shfl_xor(v, 16, 64);   // reduce across the 4 quads holding the same m
    v += __shfl_xor(v, 32, 64);
    if (lane < 16) {
      int mg = row0 + mrow + mt * 16 + lane;
      float val = v + bp;
      out[mg * 64 + ii * 8 + jj] = val;
      out[mg * 64 + jj * 8 + ii] = -val;
      if (p == 0) {
#pragma unroll
        for (int d = 0; d < 8; ++d)
          out[mg * 64 + d * 9] = 0.f;   // diagonal zeros (poisoned buffer)
      }
    }
  }
}

extern "C" void kernel_launch(void* const* d_in, const int* in_sizes, int n_in,
                              void* d_out, int out_size, void* d_ws, size_t ws_size,
                              hipStream_t stream) {
  const float* x    = (const float*)d_in[0];
  const float* W1   = (const float*)d_in[1];
  const float* b1   = (const float*)d_in[2];
  const float* Wh   = (const float*)d_in[3];
  const float* bh   = (const float*)d_in[4];
  const float* Wout = (const float*)d_in[5];
  const float* bout = (const float*)d_in[6];
  const int* rel    = (const int*)d_in[7];
  const int* iidx   = (const int*)d_in[8];
  const int* jidx   = (const int*)d_in[9];
  float* out = (float*)d_out;
  unsigned short* WT = (unsigned short*)d_ws;  // 2*28*128*128 bf16 = 1.84 MB

  prep_wt<<<dim3(56 * 16), 256, 0, stream>>>(Wh, WT);
  dim3 grid(BATCH_N / TILE_M, P_PAIRS);
  mlp_pairs<<<grid, THREADS, 0, stream>>>(x, W1, b1, bh, Wout, bout, rel, iidx, jidx, WT, out);
}

// Round 2
// 366.466 us; speedup vs baseline: 1.6247x; 1.6247x over previous
//
#include <hip/hip_runtime.h>

#define NDIM 8
#define P_PAIRS 28
#define HID 128
#define BATCH_N 65536
#define TILE_M 256
#define THREADS 512

#define LOG2E 1.4426950408889634f
#define LN2   0.6931471805599453f

typedef __attribute__((ext_vector_type(8))) short bf16x8;
typedef __attribute__((ext_vector_type(4))) float f32x4;

__device__ __forceinline__ unsigned short f32_to_bf16(float f) {
  union { float f; unsigned u; } v; v.f = f;
  unsigned r = v.u + 0x7FFFu + ((v.u >> 16) & 1u);
  return (unsigned short)(r >> 16);
}

__device__ __forceinline__ unsigned cvt_pk_bf16(float a, float b) {
  unsigned r;
  asm("v_cvt_pk_bf16_f32 %0, %1, %2" : "=v"(r) : "v"(a), "v"(b));
  return r;
}

__device__ __forceinline__ float fast_exp2(float x) {
  float r; asm("v_exp_f32 %0, %1" : "=v"(r) : "v"(x)); return r;
}
__device__ __forceinline__ float fast_log2(float x) {
  float r; asm("v_log_f32 %0, %1" : "=v"(r) : "v"(x)); return r;
}

// softplus on pre-scaled input t = z*log2(e); exact for all |z| < 88 (clamp only
// guards against inf propagation for astronomically unlikely z)
__device__ __forceinline__ float softplus_scaled(float t) {
  t = fminf(t, 126.0f);
  return LN2 * fast_log2(1.0f + fast_exp2(t));
}

// Transpose+convert+prescale: Wh (2,28,128,128) f32 -> WT bf16, WT[l][p][n][k] = Wh[l][p][k][n]*log2e
__global__ void prep_wt(const float* __restrict__ Wh, unsigned short* __restrict__ WT) {
  __shared__ float tile[32][33];
  int t = blockIdx.x;           // 56*16 blocks
  int lp = t >> 4;
  int sub = t & 15;
  int kt = (sub >> 2) * 32, nt = (sub & 3) * 32;
  const float* src = Wh + (size_t)lp * 16384;
  unsigned short* dst = WT + (size_t)lp * 16384;
  int tx = threadIdx.x & 31, ty = threadIdx.x >> 5;   // 32 x 8
#pragma unroll
  for (int r = 0; r < 32; r += 8)
    tile[r + ty][tx] = src[(kt + r + ty) * 128 + (nt + tx)];
  __syncthreads();
#pragma unroll
  for (int r = 0; r < 32; r += 8)
    dst[(nt + r + ty) * 128 + (kt + tx)] = f32_to_bf16(tile[tx][r + ty] * LOG2E);
}

__launch_bounds__(THREADS, 2)
__global__ void mlp_pairs(const float* __restrict__ x,
                          const float* __restrict__ W1,
                          const float* __restrict__ b1,
                          const float* __restrict__ bh,
                          const float* __restrict__ Wout,
                          const float* __restrict__ bout,
                          const int* __restrict__ rel_idx,
                          const int* __restrict__ i_idx,
                          const int* __restrict__ j_idx,
                          const unsigned short* __restrict__ WT,
                          float* __restrict__ out) {
  const int p = blockIdx.y;
  const int row0 = blockIdx.x * TILE_M;
  const int tid = (int)threadIdx.x;
  const int lane = tid & 63;
  const int wave = tid >> 6;          // 0..7, each wave owns 32 batch rows
  const int qd = lane >> 4;           // quad 0..3
  const int ln = lane & 15;
  const int mrow = wave * 32;

  // pitch 136 shorts = 272 B: 16B-aligned rows, <=2-way conflicts within quad phases
  __shared__ __align__(16) unsigned short w0_lds[128][136];    // 34816 B  Wh0^T [n][k]
  __shared__ __align__(16) unsigned short w1_lds[128][136];    // 34816 B  Wh1^T [n][k]
  __shared__ __align__(16) unsigned short h_lds[TILE_M][136];  // 69632 B  activations [m][k]
  __shared__ __align__(16) unsigned short xg_lds[TILE_M][8];   //  4096 B  gathered input, K pad 6->8
  __shared__ __align__(16) unsigned short w1t_lds[128][8];     //  2048 B  W1^T [n][k], K pad 6->8
  __shared__ __align__(16) float b1s[128];
  __shared__ __align__(16) float bh0s[128];
  __shared__ __align__(16) float bh1s[128];
  __shared__ __align__(16) float wouts[128];
  // total ~147.5 KB

  // ---- stage BOTH hidden-layer weight slabs (no mid-kernel restage) ----
  {
    const uint4* s0 = reinterpret_cast<const uint4*>(WT + (size_t)p * 16384);
    const uint4* s1 = reinterpret_cast<const uint4*>(WT + (size_t)(P_PAIRS + p) * 16384);
#pragma unroll
    for (int it = 0; it < 4; ++it) {
      int idx = it * THREADS + tid;    // 0..2047
      int r = idx >> 4, c = idx & 15;
      uint4 a = s0[idx];
      uint4 b = s1[idx];
      *reinterpret_cast<uint4*>(&w0_lds[r][c * 8]) = a;
      *reinterpret_cast<uint4*>(&w1_lds[r][c * 8]) = b;
    }
  }
  // ---- stage x (gathered, bf16, pad to 8), W1^T (prescaled), biases (prescaled) ----
  if (tid < TILE_M) {
    int r = tid;
    const float4* xr = reinterpret_cast<const float4*>(x + (size_t)(row0 + r) * 8);
    float4 a = xr[0], b = xr[1];
    float xv[8] = {a.x, a.y, a.z, a.w, b.x, b.y, b.z, b.w};
    unsigned short u[8];
#pragma unroll
    for (int d = 0; d < 6; ++d) {
      int rl = rel_idx[p * 6 + d];
      u[d] = f32_to_bf16(xv[rl]);
    }
    u[6] = 0; u[7] = 0;
    uint4 pk;
    pk.x = (unsigned)u[0] | ((unsigned)u[1] << 16);
    pk.y = (unsigned)u[2] | ((unsigned)u[3] << 16);
    pk.z = (unsigned)u[4] | ((unsigned)u[5] << 16);
    pk.w = 0u;
    *reinterpret_cast<uint4*>(&xg_lds[r][0]) = pk;
  } else if (tid < TILE_M + 128) {
    int n = tid - TILE_M;
    unsigned short u[8];
#pragma unroll
    for (int k = 0; k < 6; ++k)
      u[k] = f32_to_bf16(W1[(p * 6 + k) * 128 + n] * LOG2E);
    u[6] = 0; u[7] = 0;
    uint4 pk;
    pk.x = (unsigned)u[0] | ((unsigned)u[1] << 16);
    pk.y = (unsigned)u[2] | ((unsigned)u[3] << 16);
    pk.z = (unsigned)u[4] | ((unsigned)u[5] << 16);
    pk.w = 0u;
    *reinterpret_cast<uint4*>(&w1t_lds[n][0]) = pk;
  } else {
    int n = tid - (TILE_M + 128);      // 0..127
    b1s[n]  = b1[p * 128 + n] * LOG2E;
    bh0s[n] = bh[p * 128 + n] * LOG2E;
    bh1s[n] = bh[(P_PAIRS + p) * 128 + n] * LOG2E;
    wouts[n] = Wout[p * 128 + n];
  }
  __syncthreads();   // the ONLY barrier

  f32x4 acc[2][8];

  // ================= Layer 1: t1 = xg @ (W1*log2e) + b1*log2e, K padded, quad-0 frags ============
#pragma unroll
  for (int nt = 0; nt < 8; ++nt) {
    f32x4 b4 = *reinterpret_cast<const f32x4*>(&b1s[nt * 16 + qd * 4]);
    acc[0][nt] = b4;
    acc[1][nt] = b4;
  }
  {
    bf16x8 zero8 = {};
    bf16x8 bfr[2];
#pragma unroll
    for (int mt = 0; mt < 2; ++mt) {
      bfr[mt] = zero8;
      if (qd == 0)
        bfr[mt] = *reinterpret_cast<const bf16x8*>(&xg_lds[mrow + mt * 16 + ln][0]);
    }
#pragma unroll
    for (int nt = 0; nt < 8; ++nt) {
      bf16x8 afr = zero8;
      if (qd == 0)
        afr = *reinterpret_cast<const bf16x8*>(&w1t_lds[nt * 16 + ln][0]);
#pragma unroll
      for (int mt = 0; mt < 2; ++mt)
        acc[mt][nt] = __builtin_amdgcn_mfma_f32_16x16x32_bf16(afr, bfr[mt], acc[mt][nt], 0, 0, 0);
    }
  }
  // epilogue: softplus (exp2/log2 form) + packed bf16 convert -> h_lds (wave-private rows)
#pragma unroll
  for (int mt = 0; mt < 2; ++mt) {
    int m = mrow + mt * 16 + ln;
#pragma unroll
    for (int nt = 0; nt < 8; ++nt) {
      float s0 = softplus_scaled(acc[mt][nt][0]);
      float s1 = softplus_scaled(acc[mt][nt][1]);
      float s2 = softplus_scaled(acc[mt][nt][2]);
      float s3 = softplus_scaled(acc[mt][nt][3]);
      uint2 pk;
      pk.x = cvt_pk_bf16(s0, s1);
      pk.y = cvt_pk_bf16(s2, s3);
      *reinterpret_cast<uint2*>(&h_lds[m][nt * 16 + qd * 4]) = pk;
    }
  }

  // ================= Layer 2: t2 = h1 @ Wh0s + bh0s ============
#pragma unroll
  for (int nt = 0; nt < 8; ++nt) {
    f32x4 b4 = *reinterpret_cast<const f32x4*>(&bh0s[nt * 16 + qd * 4]);
    acc[0][nt] = b4;
    acc[1][nt] = b4;
  }
#pragma unroll
  for (int ks = 0; ks < 4; ++ks) {
    bf16x8 bfr[2], afr[8];
#pragma unroll
    for (int mt = 0; mt < 2; ++mt)
      bfr[mt] = *reinterpret_cast<const bf16x8*>(&h_lds[mrow + mt * 16 + ln][ks * 32 + qd * 8]);
#pragma unroll
    for (int nt = 0; nt < 8; ++nt)
      afr[nt] = *reinterpret_cast<const bf16x8*>(&w0_lds[nt * 16 + ln][ks * 32 + qd * 8]);
#pragma unroll
    for (int nt = 0; nt < 8; ++nt)
#pragma unroll
      for (int mt = 0; mt < 2; ++mt)
        acc[mt][nt] = __builtin_amdgcn_mfma_f32_16x16x32_bf16(afr[nt], bfr[mt], acc[mt][nt], 0, 0, 0);
  }
#pragma unroll
  for (int mt = 0; mt < 2; ++mt) {
    int m = mrow + mt * 16 + ln;
#pragma unroll
    for (int nt = 0; nt < 8; ++nt) {
      float s0 = softplus_scaled(acc[mt][nt][0]);
      float s1 = softplus_scaled(acc[mt][nt][1]);
      float s2 = softplus_scaled(acc[mt][nt][2]);
      float s3 = softplus_scaled(acc[mt][nt][3]);
      uint2 pk;
      pk.x = cvt_pk_bf16(s0, s1);
      pk.y = cvt_pk_bf16(s2, s3);
      *reinterpret_cast<uint2*>(&h_lds[m][nt * 16 + qd * 4]) = pk;
    }
  }

  // ================= Layer 3 + output dot (no LDS round trip for h3) ============
#pragma unroll
  for (int nt = 0; nt < 8; ++nt) {
    f32x4 b4 = *reinterpret_cast<const f32x4*>(&bh1s[nt * 16 + qd * 4]);
    acc[0][nt] = b4;
    acc[1][nt] = b4;
  }
#pragma unroll
  for (int ks = 0; ks < 4; ++ks) {
    bf16x8 bfr[2], afr[8];
#pragma unroll
    for (int mt = 0; mt < 2; ++mt)
      bfr[mt] = *reinterpret_cast<const bf16x8*>(&h_lds[mrow + mt * 16 + ln][ks * 32 + qd * 8]);
#pragma unroll
    for (int nt = 0; nt < 8; ++nt)
      afr[nt] = *reinterpret_cast<const bf16x8*>(&w1_lds[nt * 16 + ln][ks * 32 + qd * 8]);
#pragma unroll
    for (int nt = 0; nt < 8; ++nt)
#pragma unroll
      for (int mt = 0; mt < 2; ++mt)
        acc[mt][nt] = __builtin_amdgcn_mfma_f32_16x16x32_bf16(afr[nt], bfr[mt], acc[mt][nt], 0, 0, 0);
  }
  float pv[2] = {0.f, 0.f};
#pragma unroll
  for (int mt = 0; mt < 2; ++mt) {
#pragma unroll
    for (int nt = 0; nt < 8; ++nt) {
      f32x4 wo4 = *reinterpret_cast<const f32x4*>(&wouts[nt * 16 + qd * 4]);
#pragma unroll
      for (int r = 0; r < 4; ++r)
        pv[mt] += wo4[r] * softplus_scaled(acc[mt][nt][r]);
    }
  }

  const int ii = i_idx[p], jj = j_idx[p];
  const float bp = bout[p];
#pragma unroll
  for (int mt = 0; mt < 2; ++mt) {
    float v = pv[mt];
    v += __shfl_xor(v, 16, 64);   // reduce across the 4 quads holding the same m
    v += __shfl_xor(v, 32, 64);
    if (lane < 16) {
      int mg = row0 + mrow + mt * 16 + lane;
      float val = v + bp;
      out[mg * 64 + ii * 8 + jj] = val;
      out[mg * 64 + jj * 8 + ii] = -val;
      if (p == 0) {
#pragma unroll
        for (int d = 0; d < 8; ++d)
          out[mg * 64 + d * 9] = 0.f;   // diagonal zeros (poisoned buffer)
      }
    }
  }
}

extern "C" void kernel_launch(void* const* d_in, const int* in_sizes, int n_in,
                              void* d_out, int out_size, void* d_ws, size_t ws_size,
                              hipStream_t stream) {
  const float* x    = (const float*)d_in[0];
  const float* W1   = (const float*)d_in[1];
  const float* b1   = (const float*)d_in[2];
  const float* Wh   = (const float*)d_in[3];
  const float* bh   = (const float*)d_in[4];
  const float* Wout = (const float*)d_in[5];
  const float* bout = (const float*)d_in[6];
  const int* rel    = (const int*)d_in[7];
  const int* iidx   = (const int*)d_in[8];
  const int* jidx   = (const int*)d_in[9];
  float* out = (float*)d_out;
  unsigned short* WT = (unsigned short*)d_ws;  // 2*28*128*128 bf16 = 1.84 MB

  prep_wt<<<dim3(56 * 16), 256, 0, stream>>>(Wh, WT);
  dim3 grid(BATCH_N / TILE_M, P_PAIRS);
  mlp_pairs<<<grid, THREADS, 0, stream>>>(x, W1, b1, bh, Wout, bout, rel, iidx, jidx, WT, out);
}

// Round 3
// 319.336 us; speedup vs baseline: 1.8645x; 1.1476x over previous
//
#include <hip/hip_runtime.h>

#define NDIM 8
#define P_PAIRS 28
#define HID 128
#define BATCH_N 65536
#define TILE_M 256
#define THREADS 512
#define TILES_PER_BLOCK 4

#define LOG2E 1.4426950408889634f
#define LN2   0.6931471805599453f

typedef __attribute__((ext_vector_type(8))) short bf16x8;
typedef __attribute__((ext_vector_type(4))) float f32x4;

__device__ __forceinline__ unsigned short f32_to_bf16(float f) {
  union { float f; unsigned u; } v; v.f = f;
  unsigned r = v.u + 0x7FFFu + ((v.u >> 16) & 1u);
  return (unsigned short)(r >> 16);
}

__device__ __forceinline__ unsigned cvt_pk_bf16(float a, float b) {
  unsigned r;
  asm("v_cvt_pk_bf16_f32 %0, %1, %2" : "=v"(r) : "v"(a), "v"(b));
  return r;
}

__device__ __forceinline__ float fast_exp2(float x) {
  float r; asm("v_exp_f32 %0, %1" : "=v"(r) : "v"(x)); return r;
}
__device__ __forceinline__ float fast_log2(float x) {
  float r; asm("v_log_f32 %0, %1" : "=v"(r) : "v"(x)); return r;
}

// h' = log2(1 + 2^t) where t = z*log2e;  (= softplus(z)*log2e — the ln2 is folded
// into the NEXT layer: ln2*log2e == 1, so hidden weights stay unscaled)
__device__ __forceinline__ float softplus2(float t) {
  t = fminf(t, 126.0f);
  return fast_log2(1.0f + fast_exp2(t));
}

// XOR-swizzled row-major [r][128] bf16; element group c8 = k>>3 (16B granules)
__device__ __forceinline__ int swz(int r, int c8) {
  return r * 128 + (((c8 ^ (r & 15)) & 15) << 3);
}

// Transpose+convert: Wh (2,28,128,128) f32 -> WT bf16, WT[l][p][n][k] = Wh[l][p][k][n]  (unscaled)
__global__ void prep_wt(const float* __restrict__ Wh, unsigned short* __restrict__ WT) {
  __shared__ float tile[32][33];
  int t = blockIdx.x;           // 56*16 blocks
  int lp = t >> 4;
  int sub = t & 15;
  int kt = (sub >> 2) * 32, nt = (sub & 3) * 32;
  const float* src = Wh + (size_t)lp * 16384;
  unsigned short* dst = WT + (size_t)lp * 16384;
  int tx = threadIdx.x & 31, ty = threadIdx.x >> 5;   // 32 x 8
#pragma unroll
  for (int r = 0; r < 32; r += 8)
    tile[r + ty][tx] = src[(kt + r + ty) * 128 + (nt + tx)];
  __syncthreads();
#pragma unroll
  for (int r = 0; r < 32; r += 8)
    dst[(nt + r + ty) * 128 + (kt + tx)] = f32_to_bf16(tile[tx][r + ty]);
}

__launch_bounds__(THREADS, 2)
__global__ void mlp_pairs(const float* __restrict__ x,
                          const float* __restrict__ W1,
                          const float* __restrict__ b1,
                          const float* __restrict__ bh,
                          const float* __restrict__ Wout,
                          const float* __restrict__ bout,
                          const int* __restrict__ rel_idx,
                          const int* __restrict__ i_idx,
                          const int* __restrict__ j_idx,
                          const unsigned short* __restrict__ WT,
                          float* __restrict__ out) {
  const int p = blockIdx.y;
  const int bx = blockIdx.x;          // batch group: rows [bx*1024, bx*1024+1024)
  const int tid = (int)threadIdx.x;
  const int lane = tid & 63;
  const int wave = tid >> 6;          // 0..7, each wave owns 32 rows per tile
  const int qd = lane >> 4;
  const int ln = lane & 15;
  const int mrow = wave * 32;

  __shared__ __align__(16) unsigned short w0_lds[128 * 128];   // 32 KB, swizzled [n][k]
  __shared__ __align__(16) unsigned short w1_lds[128 * 128];   // 32 KB, swizzled [n][k]
  __shared__ __align__(16) unsigned short h_lds[TILE_M * 128]; // 64 KB, swizzled [m][k]
  __shared__ __align__(16) unsigned short xg_lds[TILE_M][8];   //  4 KB
  __shared__ __align__(16) unsigned short w1t_lds[128][8];     //  2 KB
  __shared__ __align__(16) float b1s[128];
  __shared__ __align__(16) float bh0s[128];
  __shared__ __align__(16) float bh1s[128];
  __shared__ __align__(16) float wouts[128];
  // total ~139.3 KB -> 1 block/CU

  // ---- stage both hidden-layer weight slabs, swizzled (ONCE per block) ----
  {
    const uint4* s0 = reinterpret_cast<const uint4*>(WT + (size_t)p * 16384);
    const uint4* s1 = reinterpret_cast<const uint4*>(WT + (size_t)(P_PAIRS + p) * 16384);
#pragma unroll
    for (int it = 0; it < 4; ++it) {
      int idx = it * THREADS + tid;    // 0..2047
      int r = idx >> 4, c = idx & 15;
      uint4 a = s0[idx];
      uint4 b = s1[idx];
      int off = swz(r, c);
      *reinterpret_cast<uint4*>(&w0_lds[off]) = a;
      *reinterpret_cast<uint4*>(&w1_lds[off]) = b;
    }
  }
  if (tid < 128) {                      // W1^T prescaled by log2e, K padded 6->8
    int n = tid;
    unsigned short u[8];
#pragma unroll
    for (int k = 0; k < 6; ++k)
      u[k] = f32_to_bf16(W1[(p * 6 + k) * 128 + n] * LOG2E);
    u[6] = 0; u[7] = 0;
    uint4 pk;
    pk.x = (unsigned)u[0] | ((unsigned)u[1] << 16);
    pk.y = (unsigned)u[2] | ((unsigned)u[3] << 16);
    pk.z = (unsigned)u[4] | ((unsigned)u[5] << 16);
    pk.w = 0u;
    *reinterpret_cast<uint4*>(&w1t_lds[n][0]) = pk;
  } else if (tid < 256) {
    int n = tid - 128;
    b1s[n]  = b1[p * 128 + n] * LOG2E;
    bh0s[n] = bh[p * 128 + n] * LOG2E;
    bh1s[n] = bh[(P_PAIRS + p) * 128 + n] * LOG2E;
    wouts[n] = Wout[p * 128 + n] * LN2;
  }
  int rl[6];
#pragma unroll
  for (int d = 0; d < 6; ++d) rl[d] = rel_idx[p * 6 + d];
  const int ii = i_idx[p], jj = j_idx[p];
  const float bp = bout[p];
  __syncthreads();   // the ONLY barrier

  // ---- prefetch tile 0's x (lane<32: 32B row) ----
  float4 xa, xb;
  {
    int row = bx * (TILE_M * TILES_PER_BLOCK) + mrow + (lane & 31);
    const float4* xr = reinterpret_cast<const float4*>(x + (size_t)row * 8);
    if (lane < 32) { xa = xr[0]; xb = xr[1]; }
  }

  for (int itile = 0; itile < TILES_PER_BLOCK; ++itile) {
    const int row0 = bx * (TILE_M * TILES_PER_BLOCK) + itile * TILE_M;

    // ---- write gathered x rows (wave-private; no barrier needed) ----
    if (lane < 32) {
      int r = mrow + lane;             // local row in tile
      float xv[8] = {xa.x, xa.y, xa.z, xa.w, xb.x, xb.y, xb.z, xb.w};
      unsigned short u[8];
#pragma unroll
      for (int d = 0; d < 6; ++d)
        u[d] = f32_to_bf16(xv[rl[d]]);
      u[6] = 0; u[7] = 0;
      uint4 pk;
      pk.x = (unsigned)u[0] | ((unsigned)u[1] << 16);
      pk.y = (unsigned)u[2] | ((unsigned)u[3] << 16);
      pk.z = (unsigned)u[4] | ((unsigned)u[5] << 16);
      pk.w = 0u;
      *reinterpret_cast<uint4*>(&xg_lds[r][0]) = pk;
    }
    // ---- prefetch next tile's x (overlaps this tile's compute) ----
    if (itile + 1 < TILES_PER_BLOCK && lane < 32) {
      int row = row0 + TILE_M + mrow + (lane & 31);
      const float4* xr = reinterpret_cast<const float4*>(x + (size_t)row * 8);
      xa = xr[0]; xb = xr[1];
    }

    f32x4 acc[2][8];

    // ===== Layer 1 =====
#pragma unroll
    for (int nt = 0; nt < 8; ++nt) {
      f32x4 b4 = *reinterpret_cast<const f32x4*>(&b1s[nt * 16 + qd * 4]);
      acc[0][nt] = b4;
      acc[1][nt] = b4;
    }
    {
      bf16x8 zero8 = {};
      bf16x8 bfr[2];
#pragma unroll
      for (int mt = 0; mt < 2; ++mt) {
        bfr[mt] = zero8;
        if (qd == 0)
          bfr[mt] = *reinterpret_cast<const bf16x8*>(&xg_lds[mrow + mt * 16 + ln][0]);
      }
#pragma unroll
      for (int nt = 0; nt < 8; ++nt) {
        bf16x8 afr = zero8;
        if (qd == 0)
          afr = *reinterpret_cast<const bf16x8*>(&w1t_lds[nt * 16 + ln][0]);
#pragma unroll
        for (int mt = 0; mt < 2; ++mt)
          acc[mt][nt] = __builtin_amdgcn_mfma_f32_16x16x32_bf16(afr, bfr[mt], acc[mt][nt], 0, 0, 0);
      }
    }
#pragma unroll
    for (int mt = 0; mt < 2; ++mt) {
      int m = mrow + mt * 16 + ln;
#pragma unroll
      for (int nt = 0; nt < 8; ++nt) {
        uint2 pk;
        pk.x = cvt_pk_bf16(softplus2(acc[mt][nt][0]), softplus2(acc[mt][nt][1]));
        pk.y = cvt_pk_bf16(softplus2(acc[mt][nt][2]), softplus2(acc[mt][nt][3]));
        int off = swz(m, nt * 2 + (qd >> 1)) + (qd & 1) * 4;
        *reinterpret_cast<uint2*>(&h_lds[off]) = pk;
      }
    }

    // ===== Layer 2 =====
#pragma unroll
    for (int nt = 0; nt < 8; ++nt) {
      f32x4 b4 = *reinterpret_cast<const f32x4*>(&bh0s[nt * 16 + qd * 4]);
      acc[0][nt] = b4;
      acc[1][nt] = b4;
    }
#pragma unroll
    for (int ks = 0; ks < 4; ++ks) {
      bf16x8 bfr[2], afr[8];
#pragma unroll
      for (int mt = 0; mt < 2; ++mt)
        bfr[mt] = *reinterpret_cast<const bf16x8*>(&h_lds[swz(mrow + mt * 16 + ln, ks * 4 + qd)]);
#pragma unroll
      for (int nt = 0; nt < 8; ++nt)
        afr[nt] = *reinterpret_cast<const bf16x8*>(&w0_lds[swz(nt * 16 + ln, ks * 4 + qd)]);
#pragma unroll
      for (int nt = 0; nt < 8; ++nt)
#pragma unroll
        for (int mt = 0; mt < 2; ++mt)
          acc[mt][nt] = __builtin_amdgcn_mfma_f32_16x16x32_bf16(afr[nt], bfr[mt], acc[mt][nt], 0, 0, 0);
    }
#pragma unroll
    for (int mt = 0; mt < 2; ++mt) {
      int m = mrow + mt * 16 + ln;
#pragma unroll
      for (int nt = 0; nt < 8; ++nt) {
        uint2 pk;
        pk.x = cvt_pk_bf16(softplus2(acc[mt][nt][0]), softplus2(acc[mt][nt][1]));
        pk.y = cvt_pk_bf16(softplus2(acc[mt][nt][2]), softplus2(acc[mt][nt][3]));
        int off = swz(m, nt * 2 + (qd >> 1)) + (qd & 1) * 4;
        *reinterpret_cast<uint2*>(&h_lds[off]) = pk;
      }
    }

    // ===== Layer 3 + output dot =====
#pragma unroll
    for (int nt = 0; nt < 8; ++nt) {
      f32x4 b4 = *reinterpret_cast<const f32x4*>(&bh1s[nt * 16 + qd * 4]);
      acc[0][nt] = b4;
      acc[1][nt] = b4;
    }
#pragma unroll
    for (int ks = 0; ks < 4; ++ks) {
      bf16x8 bfr[2], afr[8];
#pragma unroll
      for (int mt = 0; mt < 2; ++mt)
        bfr[mt] = *reinterpret_cast<const bf16x8*>(&h_lds[swz(mrow + mt * 16 + ln, ks * 4 + qd)]);
#pragma unroll
      for (int nt = 0; nt < 8; ++nt)
        afr[nt] = *reinterpret_cast<const bf16x8*>(&w1_lds[swz(nt * 16 + ln, ks * 4 + qd)]);
#pragma unroll
      for (int nt = 0; nt < 8; ++nt)
#pragma unroll
        for (int mt = 0; mt < 2; ++mt)
          acc[mt][nt] = __builtin_amdgcn_mfma_f32_16x16x32_bf16(afr[nt], bfr[mt], acc[mt][nt], 0, 0, 0);
    }
    float pv[2] = {0.f, 0.f};
#pragma unroll
    for (int mt = 0; mt < 2; ++mt) {
#pragma unroll
      for (int nt = 0; nt < 8; ++nt) {
        f32x4 wo4 = *reinterpret_cast<const f32x4*>(&wouts[nt * 16 + qd * 4]);
#pragma unroll
        for (int r = 0; r < 4; ++r)
          pv[mt] += wo4[r] * softplus2(acc[mt][nt][r]);
      }
    }

#pragma unroll
    for (int mt = 0; mt < 2; ++mt) {
      float v = pv[mt];
      v += __shfl_xor(v, 16, 64);
      v += __shfl_xor(v, 32, 64);
      if (lane < 16) {
        int mg = row0 + mrow + mt * 16 + lane;
        float val = v + bp;
        out[mg * 64 + ii * 8 + jj] = val;
        out[mg * 64 + jj * 8 + ii] = -val;
        if (p == 0) {
#pragma unroll
          for (int d = 0; d < 8; ++d)
            out[mg * 64 + d * 9] = 0.f;
        }
      }
    }
  }
}

extern "C" void kernel_launch(void* const* d_in, const int* in_sizes, int n_in,
                              void* d_out, int out_size, void* d_ws, size_t ws_size,
                              hipStream_t stream) {
  const float* x    = (const float*)d_in[0];
  const float* W1   = (const float*)d_in[1];
  const float* b1   = (const float*)d_in[2];
  const float* Wh   = (const float*)d_in[3];
  const float* bh   = (const float*)d_in[4];
  const float* Wout = (const float*)d_in[5];
  const float* bout = (const float*)d_in[6];
  const int* rel    = (const int*)d_in[7];
  const int* iidx   = (const int*)d_in[8];
  const int* jidx   = (const int*)d_in[9];
  float* out = (float*)d_out;
  unsigned short* WT = (unsigned short*)d_ws;  // 2*28*128*128 bf16 = 1.84 MB

  prep_wt<<<dim3(56 * 16), 256, 0, stream>>>(Wh, WT);
  dim3 grid(BATCH_N / (TILE_M * TILES_PER_BLOCK), P_PAIRS);   // (64, 28)
  mlp_pairs<<<grid, THREADS, 0, stream>>>(x, W1, b1, bh, Wout, bout, rel, iidx, jidx, WT, out);
}